// Round 20
// baseline (382.745 us; speedup 1.0000x reference)
//
#include <hip/hip_runtime.h>
#include <hip/hip_bf16.h>

#define N_ROWS 32768
#define M_ROWS 8192
#define D_DIM  384
#define K_NB   9
#define BN     16
#define BM     128
#define NMQ    4
#define MQ     (M_ROWS / NMQ)    // 2048 cols per block
#define TILES  (MQ / BN)         // 128
#define KS     3                 // K steps of 128

// key = y^2 - 2xy quantized: key' = (key + 256) / 2048 in [0,1]
#define QSCALE (1.0f / 2048.0f)
#define YOFF   0.125f
#define QSTEPF (2048.0f / 65535.0f)
#define QOFFB  256.0f
#define M2S    (-2.0f / 2048.0f)
#define BIGF   3.0e38f

#define BUFSZ  6144              // one private B buffer = 16 rows x 384 fp8
#define WBUF   12288             // per-wave B region (2 buffers)
#define YS_OFF 49152             // LDS offset of Ys (4 KB u16); total 53248

typedef __attribute__((ext_vector_type(4))) int      i32x4;
typedef __attribute__((ext_vector_type(8))) int      i32x8;
typedef __attribute__((ext_vector_type(4))) float    f32x4;
typedef __attribute__((ext_vector_type(4))) unsigned u32x4;

#define GLDS(SRC, DST)                                                       \
  __builtin_amdgcn_global_load_lds(                                          \
      (const __attribute__((address_space(1))) void*)(SRC),                  \
      (__attribute__((address_space(3))) void*)(DST), 16, 0, 0)

#define MF(AF, B, C)                                                         \
  __builtin_amdgcn_mfma_scale_f32_16x16x128_f8f6f4(                          \
      (AF), (B), (C), 0, 0, 0, 0x7F7F7F7F, 0, 0x7F7F7F7F)

// ---- prep: f32 -> fp8(e4m3) rows (k-linear) + exact f32 norms ----
__global__ __launch_bounds__(256) void FAPM_prep8(
    const float* __restrict__ emb, const float* __restrict__ mem,
    unsigned* __restrict__ A8, unsigned* __restrict__ B8,
    float* __restrict__ xn, float* __restrict__ yn) {
  const int lane = threadIdx.x & 63;
  const int row  = blockIdx.x * 4 + (threadIdx.x >> 6);
  const float* src;
  unsigned* dst;
  float* nptr;
  if (row < N_ROWS) {
    src = emb + (size_t)row * D_DIM; dst = A8 + (size_t)row * 96; nptr = xn + row;
  } else {
    int r = row - N_ROWS;
    src = mem + (size_t)r * D_DIM; dst = B8 + (size_t)r * 96; nptr = yn + r;
  }
  float s = 0.f;
  {
    int dw = lane;  // dwords 0..63
    f32x4 v = *(const f32x4*)(src + dw * 4);
    s += v.x * v.x + v.y * v.y + v.z * v.z + v.w * v.w;
    int pk = __builtin_amdgcn_cvt_pk_fp8_f32(v.x, v.y, 0, false);
    pk = __builtin_amdgcn_cvt_pk_fp8_f32(v.z, v.w, pk, true);
    dst[dw] = (unsigned)pk;
  }
  if (lane < 32) {
    int dw = lane + 64;  // dwords 64..95
    f32x4 v = *(const f32x4*)(src + dw * 4);
    s += v.x * v.x + v.y * v.y + v.z * v.z + v.w * v.w;
    int pk = __builtin_amdgcn_cvt_pk_fp8_f32(v.x, v.y, 0, false);
    pk = __builtin_amdgcn_cvt_pk_fp8_f32(v.z, v.w, pk, true);
    dst[dw] = (unsigned)pk;
  }
#pragma unroll
  for (int dd = 1; dd < 64; dd <<= 1) s += __shfl_xor(s, dd);
  if (lane == 0) *nptr = s;
}

// packed u16 min/max
__device__ __forceinline__ unsigned pkmin(unsigned a, unsigned b) {
  unsigned d;
  asm("v_pk_min_u16 %0, %1, %2" : "=v"(d) : "v"(a), "v"(b));
  return d;
}
__device__ __forceinline__ unsigned pkmax(unsigned a, unsigned b) {
  unsigned d;
  asm("v_pk_max_u16 %0, %1, %2" : "=v"(d) : "v"(a), "v"(b));
  return d;
}

// ---- 16-lane merge of per-lane sorted u16 lists; writes f32 key ascending ----
__device__ __forceinline__ void merge16i(unsigned t[9], float* dst, int sub) {
  for (int s = 0; s < K_NB; ++s) {
    unsigned m  = t[0];
    int      ml = sub;
#pragma unroll
    for (int dd = 1; dd < 16; dd <<= 1) {
      unsigned ov = (unsigned)__shfl_xor((int)m, dd);
      int      ol = __shfl_xor(ml, dd);
      bool take = (ov < m) || (ov == m && ol < ml);
      m  = take ? ov : m;
      ml = take ? ol : ml;
    }
    if (sub == ml) {
#pragma unroll
      for (int j = 0; j < 8; ++j) t[j] = t[j + 1];
      t[8] = 0xFFFFu;
    }
    if (sub == 0) dst[s] = (float)m * QSTEPF - QOFFB;  // key = y^2 - 2xy
  }
}

// stage one private 16-col B tile (6 x 16B per lane) at global base GB into
// LDS offset DSTO (wave-private; offsets {ks*128+h*16} are immediates).
#define STAGE_B(GB, DSTO)                                                    \
  {                                                                          \
    GLDS((GB), LDS + (DSTO));                                                \
    GLDS((GB) + 16, LDS + (DSTO) + 1024);                                    \
    GLDS((GB) + 128, LDS + (DSTO) + 2048);                                   \
    GLDS((GB) + 144, LDS + (DSTO) + 3072);                                   \
    GLDS((GB) + 256, LDS + (DSTO) + 4096);                                   \
    GLDS((GB) + 272, LDS + (DSTO) + 5120);                                   \
  }

// ---- fused: MX-fp8 K=128, 32 rows/wave, PRIVATE B tiles, zero-barrier loop ----
__global__ __launch_bounds__(256, 3) void FAPM_fused(
    const unsigned char* __restrict__ A8, const unsigned char* __restrict__ B8,
    const float* __restrict__ yn, float* __restrict__ part) {
  // [0,48K): per-wave private B regions (wave w: [w*12K, w*12K+12K), two 6K
  //          buffers). A-prologue reuses [0,24K) before B priming.
  //          B subtile unit 1KB = one (ks,h) chunk-column: lane l's 16B at
  //          unit + l*16 holds row (l&15), k = ks*128 + (l>>4)*32 + h*16.
  // [48K,52K): Ys as unorm16 of (y^2/2048 + 0.125), 2048 entries.
  __shared__ __attribute__((aligned(128))) unsigned char LDS[53248];
  const int tid  = threadIdx.x;
  const int lane = tid & 63;
  const int w    = tid >> 6;          // wave 0..3
  const int sub  = lane & 15;
  const int grp  = lane >> 4;
  const int bx   = blockIdx.x;
  const int mq   = bx & (NMQ - 1);
  const int row0 = (bx >> 2) * BM;    // wave owns rows row0 + w*32 .. +31
  const int colbase = mq * MQ;

  // ---- Ys region: 8 y-norms per thread -> unorm16 of key-offset form ----
  {
    const float* yp = yn + colbase + tid * 8;
    f32x4 v0 = *(const f32x4*)yp;
    f32x4 v1 = *(const f32x4*)(yp + 4);
    float a0 = fmaf(v0.x, QSCALE, YOFF), a1 = fmaf(v0.y, QSCALE, YOFF);
    float a2 = fmaf(v0.z, QSCALE, YOFF), a3 = fmaf(v0.w, QSCALE, YOFF);
    float a4 = fmaf(v1.x, QSCALE, YOFF), a5 = fmaf(v1.y, QSCALE, YOFF);
    float a6 = fmaf(v1.z, QSCALE, YOFF), a7 = fmaf(v1.w, QSCALE, YOFF);
    unsigned q0, q1, q2, q3;
    asm("v_cvt_pknorm_u16_f32 %0, %1, %2" : "=v"(q0) : "v"(a0), "v"(a1));
    asm("v_cvt_pknorm_u16_f32 %0, %1, %2" : "=v"(q1) : "v"(a2), "v"(a3));
    asm("v_cvt_pknorm_u16_f32 %0, %1, %2" : "=v"(q2) : "v"(a4), "v"(a5));
    asm("v_cvt_pknorm_u16_f32 %0, %1, %2" : "=v"(q3) : "v"(a6), "v"(a7));
    *(u32x4*)(&LDS[YS_OFF + tid * 16]) = (u32x4){q0, q1, q2, q3};
  }

  i32x8 af[2][KS];  // 48 regs: 2 row-blocks of 16, 3 K-steps of 128

  // ---- stage + read A: 2 rounds of 64 rows through [0,24K) (barriered) ----
#pragma unroll
  for (int r = 0; r < 2; ++r) {
    const unsigned char* asrc =
        A8 + (size_t)(row0 + r * 64 + w * 16 + sub) * D_DIM + grp * 32;
#pragma unroll
    for (int ks = 0; ks < KS; ++ks)
#pragma unroll
      for (int h = 0; h < 2; ++h)
        GLDS(asrc + ks * 128 + h * 16, LDS + (w * 6 + ks * 2 + h) * 1024);
    asm volatile("s_waitcnt vmcnt(0)" ::: "memory");
    __syncthreads();
    if ((w >> 1) == r) {
#pragma unroll
      for (int rbl = 0; rbl < 2; ++rbl) {
        const int g = (w & 1) * 2 + rbl;
#pragma unroll
        for (int ks = 0; ks < KS; ++ks) {
          const unsigned char* p = LDS + (g * 6 + ks * 2) * 1024 + lane * 16;
          *(i32x4*)&af[rbl][ks] = *(const i32x4*)p;
          *((i32x4*)&af[rbl][ks] + 1) = *(const i32x4*)(p + 1024);
        }
      }
    }
    __syncthreads();  // reads drained before next overwrite / B priming
  }

  // ---- private B pipeline: prime tile 0 then tile 1 (FIFO for vmcnt) ----
  const unsigned char* gb =
      B8 + (size_t)(colbase + sub) * D_DIM + grp * 32;   // tile stride 6144
  const int wbase = w * WBUF;
  STAGE_B(gb, wbase);                  // tile 0 -> buf0
  STAGE_B(gb + 6144, wbase + BUFSZ);   // tile 1 -> buf1
  const unsigned char* gbs = gb + 2 * 6144;  // next tile to stage (t+2)

  unsigned tkp[4][9];  // packed (rbl0 lo, rbl1 hi) top-9 keys, rows grp*4+i / +16
#pragma unroll
  for (int i = 0; i < 4; ++i)
#pragma unroll
    for (int j = 0; j < 9; ++j) tkp[i][j] = 0xFFFFFFFFu;

  // ---- zero-barrier main loop: each wave free-runs its own pipeline ----
  for (int t = 0; t < TILES; ++t) {
    const int bufo = wbase + (t & 1) * BUFSZ;
    if (t + 1 < TILES) asm volatile("s_waitcnt vmcnt(6)" ::: "memory");
    else               asm volatile("s_waitcnt vmcnt(0)" ::: "memory");

    // read this tile's B fragments + y-norm into registers
    const unsigned char* br = LDS + bufo + lane * 16;
    i32x8 b0, b1, b2;
    *(i32x4*)&b0 = *(const i32x4*)br;
    *((i32x4*)&b0 + 1) = *(const i32x4*)(br + 1024);
    *(i32x4*)&b1 = *(const i32x4*)(br + 2048);
    *((i32x4*)&b1 + 1) = *(const i32x4*)(br + 3072);
    *(i32x4*)&b2 = *(const i32x4*)(br + 4096);
    *((i32x4*)&b2 + 1) = *(const i32x4*)(br + 5120);
    unsigned yu = *(const unsigned short*)(
        &LDS[YS_OFF + ((t * BN + sub) << 1)]);
    float ysv = (float)yu * (1.0f / 65535.0f);

    // all LDS reads of this buffer complete -> safe to refill it
    asm volatile("s_waitcnt lgkmcnt(0)" ::: "memory");
    if (t + 2 < TILES) {
      STAGE_B(gbs, bufo);
      gbs += 6144;
    }

    // compute: 6 MFMAs (register-only) + topk
    f32x4 acc0 = {0.f, 0.f, 0.f, 0.f}, acc1 = {0.f, 0.f, 0.f, 0.f};
    acc0 = MF(af[0][0], b0, acc0);
    acc1 = MF(af[1][0], b0, acc1);
    acc0 = MF(af[0][1], b1, acc0);
    acc1 = MF(af[1][1], b1, acc1);
    acc0 = MF(af[0][2], b2, acc0);
    acc1 = MF(af[1][2], b2, acc1);

#pragma unroll
    for (int i = 0; i < 4; ++i) {
      float d2a = fmaf(acc0[i], M2S, ysv);
      float d2b = fmaf(acc1[i], M2S, ysv);
      unsigned dp;
      asm("v_cvt_pknorm_u16_f32 %0, %1, %2" : "=v"(dp) : "v"(d2a), "v"(d2b));
#pragma unroll
      for (int j = 8; j >= 1; --j)
        tkp[i][j] = pkmin(tkp[i][j], pkmax(dp, tkp[i][j - 1]));
      tkp[i][0] = pkmin(tkp[i][0], dp);
    }
  }

  // ---- unpack + per-row merge across 16 sub-lanes; write f32 key partials ----
  float* pbase = part + (size_t)mq * N_ROWS * K_NB;
#pragma unroll
  for (int i = 0; i < 4; ++i) {
    unsigned ta[9], tb[9];
#pragma unroll
    for (int j = 0; j < 9; ++j) { ta[j] = tkp[i][j] & 0xFFFFu; tb[j] = tkp[i][j] >> 16; }
    int rowA = row0 + w * 32 + grp * 4 + i;
    merge16i(ta, pbase + (size_t)rowA * K_NB, sub);
    merge16i(tb, pbase + (size_t)(rowA + 16) * K_NB, sub);
  }
}

// ------- merge the four M-quarter partials, add x^2, sqrt, final output -------
__global__ __launch_bounds__(256) void FAPM_merge4(
    const float* __restrict__ part, const float* __restrict__ xn,
    float* __restrict__ out) {
  const int r = blockIdx.x * 256 + threadIdx.x;
  const float xr = xn[r];
  float l[4][9];
#pragma unroll
  for (int q = 0; q < 4; ++q)
#pragma unroll
    for (int j = 0; j < 9; ++j)
      l[q][j] = part[(size_t)q * N_ROWS * K_NB + (size_t)r * K_NB + j];
#pragma unroll
  for (int s = 0; s < K_NB; ++s) {
    float m = fminf(fminf(l[0][0], l[1][0]), fminf(l[2][0], l[3][0]));
    out[(size_t)r * K_NB + s] = sqrtf(fmaxf(m + xr, 0.f));
    bool t0 = (l[0][0] == m);
    bool t1 = (l[1][0] == m) && !t0;
    bool t2 = (l[2][0] == m) && !t0 && !t1;
    bool t3 = !(t0 || t1 || t2);
#pragma unroll
    for (int j = 0; j < 8; ++j) {
      l[0][j] = t0 ? l[0][j + 1] : l[0][j];
      l[1][j] = t1 ? l[1][j + 1] : l[1][j];
      l[2][j] = t2 ? l[2][j + 1] : l[2][j];
      l[3][j] = t3 ? l[3][j + 1] : l[3][j];
    }
    l[0][8] = t0 ? BIGF : l[0][8];
    l[1][8] = t1 ? BIGF : l[1][8];
    l[2][8] = t2 ? BIGF : l[2][8];
    l[3][8] = t3 ? BIGF : l[3][8];
  }
}

extern "C" void kernel_launch(void* const* d_in, const int* in_sizes, int n_in,
                              void* d_out, int out_size, void* d_ws, size_t ws_size,
                              hipStream_t stream) {
  const float* emb = (const float*)d_in[0];
  const float* mem = (const float*)d_in[1];
  float* out = (float*)d_out;
  char* ws = (char*)d_ws;
  size_t offA = 0;
  size_t offB = offA + (size_t)N_ROWS * D_DIM;       // A8: 12,582,912
  size_t offX = offB + (size_t)M_ROWS * D_DIM;       // B8: +3,145,728
  size_t offY = offX + (size_t)N_ROWS * 4;           // +131,072
  size_t offP = offY + (size_t)M_ROWS * 4;           // +32,768
  // partials: 4 quarters x N x 9 f32 = 4,718,592  (total ~20.6 MB)
  unsigned char* A8 = (unsigned char*)(ws + offA);
  unsigned char* B8 = (unsigned char*)(ws + offB);
  float* xn = (float*)(ws + offX);
  float* yn = (float*)(ws + offY);
  float* part = (float*)(ws + offP);

  FAPM_prep8<<<(N_ROWS + M_ROWS) / 4, 256, 0, stream>>>(
      emb, mem, (unsigned*)A8, (unsigned*)B8, xn, yn);
  FAPM_fused<<<(N_ROWS / BM) * NMQ, 256, 0, stream>>>(A8, B8, yn, part);
  FAPM_merge4<<<N_ROWS / 256, 256, 0, stream>>>(part, xn, out);
}

// Round 21
// 182.765 us; speedup vs baseline: 2.0942x; 2.0942x over previous
//
#include <hip/hip_runtime.h>
#include <hip/hip_bf16.h>

#define N_ROWS 32768
#define M_ROWS 8192
#define D_DIM  384
#define K_NB   9
#define BN     32
#define BM     128
#define NMQ    4
#define MQ     (M_ROWS / NMQ)    // 2048 cols per block
#define TILES  (MQ / BN)         // 64
#define KS     3                 // K steps of 128

// key = y^2 - 2xy quantized: key' = (key + 256) / 2048 in [0,1]
#define QSCALE (1.0f / 2048.0f)
#define YOFF   0.125f
#define QSTEPF (2048.0f / 65535.0f)
#define QOFFB  256.0f
#define M2S    (-2.0f / 2048.0f)
#define BIGF   3.0e38f

#define BUFSZ  12288             // one B buffer = 32 rows x 384 fp8 (= tile stride)
#define YS_OFF 24576             // LDS offset of Ys (4 KB u16); total LDS 28672

typedef __attribute__((ext_vector_type(4))) int      i32x4;
typedef __attribute__((ext_vector_type(8))) int      i32x8;
typedef __attribute__((ext_vector_type(4))) float    f32x4;
typedef __attribute__((ext_vector_type(4))) unsigned u32x4;

#define GLDS(SRC, DST)                                                       \
  __builtin_amdgcn_global_load_lds(                                          \
      (const __attribute__((address_space(1))) void*)(SRC),                  \
      (__attribute__((address_space(3))) void*)(DST), 16, 0, 0)

#define MF(AF, B, C)                                                         \
  __builtin_amdgcn_mfma_scale_f32_16x16x128_f8f6f4(                          \
      (AF), (B), (C), 0, 0, 0, 0x7F7F7F7F, 0, 0x7F7F7F7F)

// ---- prep: f32 -> fp8(e4m3) rows (k-linear) + exact f32 norms ----
__global__ __launch_bounds__(256) void FAPM_prep8(
    const float* __restrict__ emb, const float* __restrict__ mem,
    unsigned* __restrict__ A8, unsigned* __restrict__ B8,
    float* __restrict__ xn, float* __restrict__ yn) {
  const int lane = threadIdx.x & 63;
  const int row  = blockIdx.x * 4 + (threadIdx.x >> 6);
  const float* src;
  unsigned* dst;
  float* nptr;
  if (row < N_ROWS) {
    src = emb + (size_t)row * D_DIM; dst = A8 + (size_t)row * 96; nptr = xn + row;
  } else {
    int r = row - N_ROWS;
    src = mem + (size_t)r * D_DIM; dst = B8 + (size_t)r * 96; nptr = yn + r;
  }
  float s = 0.f;
  {
    int dw = lane;  // dwords 0..63
    f32x4 v = *(const f32x4*)(src + dw * 4);
    s += v.x * v.x + v.y * v.y + v.z * v.z + v.w * v.w;
    int pk = __builtin_amdgcn_cvt_pk_fp8_f32(v.x, v.y, 0, false);
    pk = __builtin_amdgcn_cvt_pk_fp8_f32(v.z, v.w, pk, true);
    dst[dw] = (unsigned)pk;
  }
  if (lane < 32) {
    int dw = lane + 64;  // dwords 64..95
    f32x4 v = *(const f32x4*)(src + dw * 4);
    s += v.x * v.x + v.y * v.y + v.z * v.z + v.w * v.w;
    int pk = __builtin_amdgcn_cvt_pk_fp8_f32(v.x, v.y, 0, false);
    pk = __builtin_amdgcn_cvt_pk_fp8_f32(v.z, v.w, pk, true);
    dst[dw] = (unsigned)pk;
  }
#pragma unroll
  for (int dd = 1; dd < 64; dd <<= 1) s += __shfl_xor(s, dd);
  if (lane == 0) *nptr = s;
}

// packed u16 min/max
__device__ __forceinline__ unsigned pkmin(unsigned a, unsigned b) {
  unsigned d;
  asm("v_pk_min_u16 %0, %1, %2" : "=v"(d) : "v"(a), "v"(b));
  return d;
}
__device__ __forceinline__ unsigned pkmax(unsigned a, unsigned b) {
  unsigned d;
  asm("v_pk_max_u16 %0, %1, %2" : "=v"(d) : "v"(a), "v"(b));
  return d;
}

// ---- 16-lane merge of per-lane sorted u16 lists; writes f32 key ascending ----
__device__ __forceinline__ void merge16i(unsigned t[9], float* dst, int sub) {
  for (int s = 0; s < K_NB; ++s) {
    unsigned m  = t[0];
    int      ml = sub;
#pragma unroll
    for (int dd = 1; dd < 16; dd <<= 1) {
      unsigned ov = (unsigned)__shfl_xor((int)m, dd);
      int      ol = __shfl_xor(ml, dd);
      bool take = (ov < m) || (ov == m && ol < ml);
      m  = take ? ov : m;
      ml = take ? ol : ml;
    }
    if (sub == ml) {
#pragma unroll
      for (int j = 0; j < 8; ++j) t[j] = t[j + 1];
      t[8] = 0xFFFFu;
    }
    if (sub == 0) dst[s] = (float)m * QSTEPF - QOFFB;  // key = y^2 - 2xy
  }
}

// ------- fused: MX-fp8 K=128, 32 rows/wave, <=128 regs -> 4 waves/SIMD -------
__global__ __launch_bounds__(256, 4) void FAPM_fused(
    const unsigned char* __restrict__ A8, const unsigned char* __restrict__ B8,
    const float* __restrict__ yn, float* __restrict__ part) {
  // [0,24K): A staging window (prologue, 2 rounds of 64 rows), then
  //          B buf0 [0,12K) / buf1 [12K,24K). Subtile unit 1KB = 16 rows x
  //          one (ks,h) chunk-column; lane l's 16B at subtile + l*16 holds
  //          row (l&15), k = ks*128 + (l>>4)*32 + h*16 .. +15.
  // [24K,28K): Ys as unorm16 of (y^2/2048 + 0.125), 2048 entries.
  __shared__ __attribute__((aligned(128))) unsigned char LDS[28672];
  const int tid  = threadIdx.x;
  const int lane = tid & 63;
  const int w    = tid >> 6;          // wave 0..3
  const int sub  = lane & 15;
  const int grp  = lane >> 4;
  const int bx   = blockIdx.x;
  const int mq   = bx & (NMQ - 1);
  const int row0 = (bx >> 2) * BM;    // wave owns rows row0 + w*32 .. +31
  const int colbase = mq * MQ;

  // ---- Ys region: 8 y-norms per thread -> unorm16 of key-offset form ----
  {
    const float* yp = yn + colbase + tid * 8;
    f32x4 v0 = *(const f32x4*)yp;
    f32x4 v1 = *(const f32x4*)(yp + 4);
    float a0 = fmaf(v0.x, QSCALE, YOFF), a1 = fmaf(v0.y, QSCALE, YOFF);
    float a2 = fmaf(v0.z, QSCALE, YOFF), a3 = fmaf(v0.w, QSCALE, YOFF);
    float a4 = fmaf(v1.x, QSCALE, YOFF), a5 = fmaf(v1.y, QSCALE, YOFF);
    float a6 = fmaf(v1.z, QSCALE, YOFF), a7 = fmaf(v1.w, QSCALE, YOFF);
    unsigned q0, q1, q2, q3;
    asm("v_cvt_pknorm_u16_f32 %0, %1, %2" : "=v"(q0) : "v"(a0), "v"(a1));
    asm("v_cvt_pknorm_u16_f32 %0, %1, %2" : "=v"(q1) : "v"(a2), "v"(a3));
    asm("v_cvt_pknorm_u16_f32 %0, %1, %2" : "=v"(q2) : "v"(a4), "v"(a5));
    asm("v_cvt_pknorm_u16_f32 %0, %1, %2" : "=v"(q3) : "v"(a6), "v"(a7));
    *(u32x4*)(&LDS[YS_OFF + tid * 16]) = (u32x4){q0, q1, q2, q3};
  }

  i32x8 af[2][KS];  // 48 regs: 2 row-blocks of 16, 3 K-steps of 128

  // ---- stage + read A: 2 rounds of 64 rows through [0,24K) ----
  // Round r: wave w stages group g=w (rows rowbase + w*16 + sub), all 6
  // (ks,h) slots. After sync, waves with (w>>1)==r read their 2 groups.
#pragma unroll
  for (int r = 0; r < 2; ++r) {
    const unsigned char* asrc =
        A8 + (size_t)(row0 + r * 64 + w * 16 + sub) * D_DIM + grp * 32;
#pragma unroll
    for (int ks = 0; ks < KS; ++ks)
#pragma unroll
      for (int h = 0; h < 2; ++h)
        GLDS(asrc + ks * 128 + h * 16, LDS + (w * 6 + ks * 2 + h) * 1024);
    asm volatile("s_waitcnt vmcnt(0)" ::: "memory");
    __syncthreads();
    if ((w >> 1) == r) {
#pragma unroll
      for (int rbl = 0; rbl < 2; ++rbl) {
        const int g = (w & 1) * 2 + rbl;
#pragma unroll
        for (int ks = 0; ks < KS; ++ks) {
          const unsigned char* p = LDS + (g * 6 + ks * 2) * 1024 + lane * 16;
          *(i32x4*)&af[rbl][ks] = *(const i32x4*)p;
          *((i32x4*)&af[rbl][ks] + 1) = *(const i32x4*)(p + 1024);
        }
      }
    }
    __syncthreads();  // reads drained before next overwrite
  }

  // ---- per-wave B staging plan: 3 of the 12 1KB units per tile ----
  // unit u = w*3+j: cb = u/6, ks = (u%6)>>1, h = u&1
  const unsigned char* bp0;
  const unsigned char* bp1;
  const unsigned char* bp2;
  int bd0, bd1, bd2;
  {
#pragma unroll
    for (int j = 0; j < 3; ++j) {
      int uu = w * 3 + j;
      int cb = uu / 6;
      int rem = uu - cb * 6;
      int ks = rem >> 1, h = rem & 1;
      const unsigned char* sp =
          B8 + (size_t)(colbase + cb * 16 + sub) * D_DIM + grp * 32 + ks * 128 + h * 16;
      int df = uu * 1024;
      if (j == 0) { bp0 = sp; bd0 = df; }
      else if (j == 1) { bp1 = sp; bd1 = df; }
      else { bp2 = sp; bd2 = df; }
    }
  }

  // ---- prime 2-deep B pipeline: ALL of tile 0, THEN all of tile 1 ----
  GLDS(bp0, LDS + bd0); GLDS(bp1, LDS + bd1); GLDS(bp2, LDS + bd2);
  GLDS(bp0 + BUFSZ, LDS + BUFSZ + bd0);
  GLDS(bp1 + BUFSZ, LDS + BUFSZ + bd1);
  GLDS(bp2 + BUFSZ, LDS + BUFSZ + bd2);
  bp0 += 2 * BUFSZ; bp1 += 2 * BUFSZ; bp2 += 2 * BUFSZ;

  unsigned tkp[4][9];  // packed (rbl0 lo, rbl1 hi) top-9 keys, rows grp*4+i / +16
#pragma unroll
  for (int i = 0; i < 4; ++i)
#pragma unroll
    for (int j = 0; j < 9; ++j) tkp[i][j] = 0xFFFFFFFFu;

  for (int t = 0; t < TILES; ++t) {
    const int bufo = (t & 1) * BUFSZ;
    if (t + 1 < TILES) asm volatile("s_waitcnt vmcnt(3)" ::: "memory");
    else               asm volatile("s_waitcnt vmcnt(0)" ::: "memory");
    __builtin_amdgcn_s_barrier();

    const unsigned char* br = LDS + bufo + lane * 16;
#pragma unroll
    for (int cb = 0; cb < 2; ++cb) {
      unsigned yu = *(const unsigned short*)(
          &LDS[YS_OFF + ((t * BN + cb * 16 + sub) << 1)]);
      float ysv = (float)yu * (1.0f / 65535.0f);

      f32x4 acc0 = {0.f, 0.f, 0.f, 0.f}, acc1 = {0.f, 0.f, 0.f, 0.f};
      __builtin_amdgcn_s_setprio(1);
#pragma unroll
      for (int ks = 0; ks < KS; ++ks) {
        i32x8 b;
        const unsigned char* p = br + cb * 6144 + ks * 2048;
        *(i32x4*)&b = *(const i32x4*)p;
        *((i32x4*)&b + 1) = *(const i32x4*)(p + 1024);
        acc0 = MF(af[0][ks], b, acc0);
        acc1 = MF(af[1][ks], b, acc1);
      }
      __builtin_amdgcn_s_setprio(0);

#pragma unroll
      for (int i = 0; i < 4; ++i) {
        float d2a = fmaf(acc0[i], M2S, ysv);
        float d2b = fmaf(acc1[i], M2S, ysv);
        unsigned dp;
        asm("v_cvt_pknorm_u16_f32 %0, %1, %2" : "=v"(dp) : "v"(d2a), "v"(d2b));
#pragma unroll
        for (int j = 8; j >= 1; --j)
          tkp[i][j] = pkmin(tkp[i][j], pkmax(dp, tkp[i][j - 1]));
        tkp[i][0] = pkmin(tkp[i][0], dp);
      }
    }
    __builtin_amdgcn_s_barrier();  // all waves done reading buf[t&1]

    if (t + 2 < TILES) {
      GLDS(bp0, LDS + bufo + bd0);
      GLDS(bp1, LDS + bufo + bd1);
      GLDS(bp2, LDS + bufo + bd2);
      bp0 += BUFSZ; bp1 += BUFSZ; bp2 += BUFSZ;
    }
  }

  // ---- unpack + per-row merge across 16 sub-lanes; write f32 key partials ----
  float* pbase = part + (size_t)mq * N_ROWS * K_NB;
#pragma unroll
  for (int i = 0; i < 4; ++i) {
    unsigned ta[9], tb[9];
#pragma unroll
    for (int j = 0; j < 9; ++j) { ta[j] = tkp[i][j] & 0xFFFFu; tb[j] = tkp[i][j] >> 16; }
    int rowA = row0 + w * 32 + grp * 4 + i;
    merge16i(ta, pbase + (size_t)rowA * K_NB, sub);
    merge16i(tb, pbase + (size_t)(rowA + 16) * K_NB, sub);
  }
}

// ------- merge the four M-quarter partials, add x^2, sqrt, final output -------
__global__ __launch_bounds__(256) void FAPM_merge4(
    const float* __restrict__ part, const float* __restrict__ xn,
    float* __restrict__ out) {
  const int r = blockIdx.x * 256 + threadIdx.x;
  const float xr = xn[r];
  float l[4][9];
#pragma unroll
  for (int q = 0; q < 4; ++q)
#pragma unroll
    for (int j = 0; j < 9; ++j)
      l[q][j] = part[(size_t)q * N_ROWS * K_NB + (size_t)r * K_NB + j];
#pragma unroll
  for (int s = 0; s < K_NB; ++s) {
    float m = fminf(fminf(l[0][0], l[1][0]), fminf(l[2][0], l[3][0]));
    out[(size_t)r * K_NB + s] = sqrtf(fmaxf(m + xr, 0.f));
    bool t0 = (l[0][0] == m);
    bool t1 = (l[1][0] == m) && !t0;
    bool t2 = (l[2][0] == m) && !t0 && !t1;
    bool t3 = !(t0 || t1 || t2);
#pragma unroll
    for (int j = 0; j < 8; ++j) {
      l[0][j] = t0 ? l[0][j + 1] : l[0][j];
      l[1][j] = t1 ? l[1][j + 1] : l[1][j];
      l[2][j] = t2 ? l[2][j + 1] : l[2][j];
      l[3][j] = t3 ? l[3][j + 1] : l[3][j];
    }
    l[0][8] = t0 ? BIGF : l[0][8];
    l[1][8] = t1 ? BIGF : l[1][8];
    l[2][8] = t2 ? BIGF : l[2][8];
    l[3][8] = t3 ? BIGF : l[3][8];
  }
}

extern "C" void kernel_launch(void* const* d_in, const int* in_sizes, int n_in,
                              void* d_out, int out_size, void* d_ws, size_t ws_size,
                              hipStream_t stream) {
  const float* emb = (const float*)d_in[0];
  const float* mem = (const float*)d_in[1];
  float* out = (float*)d_out;
  char* ws = (char*)d_ws;
  size_t offA = 0;
  size_t offB = offA + (size_t)N_ROWS * D_DIM;       // A8: 12,582,912
  size_t offX = offB + (size_t)M_ROWS * D_DIM;       // B8: +3,145,728
  size_t offY = offX + (size_t)N_ROWS * 4;           // +131,072
  size_t offP = offY + (size_t)M_ROWS * 4;           // +32,768
  // partials: 4 quarters x N x 9 f32 = 4,718,592  (total ~20.6 MB)
  unsigned char* A8 = (unsigned char*)(ws + offA);
  unsigned char* B8 = (unsigned char*)(ws + offB);
  float* xn = (float*)(ws + offX);
  float* yn = (float*)(ws + offY);
  float* part = (float*)(ws + offP);

  FAPM_prep8<<<(N_ROWS + M_ROWS) / 4, 256, 0, stream>>>(
      emb, mem, (unsigned*)A8, (unsigned*)B8, xn, yn);
  FAPM_fused<<<(N_ROWS / BM) * NMQ, 256, 0, stream>>>(A8, B8, yn, part);
  FAPM_merge4<<<N_ROWS / 256, 256, 0, stream>>>(part, xn, out);
}